// Round 9
// baseline (422.440 us; speedup 1.0000x reference)
//
#include <hip/hip_runtime.h>
#include <math.h>

// Problem constants
#define TT 8
#define NTOK 32768
#define DD 128
#define LCOMP 8
#define GSZ 8192
#define CDIM 64
#define EDIM 128
#define NPART 32

#define TOKB 64                       // tokens per tile
#define TILES 4                       // tiles per block
#define NBLK (TT*NTOK/(TOKB*TILES))   // 1024

// workspace byte offsets
#define O_CZERO 0                            // 64 f32
#define O_W2BT  256                          // 64*128 bf16 = 16KB  [k][j]
#define O_W1BT  (256 + EDIM*CDIM*2)          // 128*128 bf16 = 32KB [j][d] swizzled
#define O_CSUMP (O_W1BT + DD*EDIM*2)         // 32*64*64 f32 = 512KB

typedef __attribute__((ext_vector_type(8))) short bf16x8;
typedef __attribute__((ext_vector_type(4))) float f32x4;

__device__ __forceinline__ ushort f2bf(float f) {
    union { float f; uint u; } c; c.f = f;
    uint u = c.u;
    return (ushort)((u + 0x7FFFu + ((u >> 16) & 1u)) >> 16);
}

// gelu via Abramowitz-Stegun 7.1.26 erf (|eps| <= 1.5e-7)
__device__ __forceinline__ float gelu_f(float a) {
    float x = a * 0.70710678118654752f;
    float ax = fabsf(x);
    float t = 1.0f / (1.0f + 0.3275911f * ax);
    float p = t * (0.254829592f + t * (-0.284496736f + t * (1.421413741f +
              t * (-1.453152027f + t * 1.061405429f))));
    float e = __expf(-x * x);
    float er = copysignf(1.0f - p * e, x);
    return 0.5f * a * (1.0f + er);
}

// ---------------- prep: bf16 transposed weights, czero, zero csum_p ---------
__global__ void prep_kernel(const float* __restrict__ w1, const float* __restrict__ b1,
                            const float* __restrict__ w2,
                            ushort* __restrict__ w1bt, ushort* __restrict__ w2bt,
                            float* __restrict__ czero, float* __restrict__ csum_p) {
    int gid = blockIdx.x * 256 + threadIdx.x;
    if (gid < DD * EDIM) {                 // w1bt[j][d], 16B-chunk XOR swizzled by (j&7)
        int j = gid >> 7, d = gid & 127;
        int slot = (d >> 3) ^ (j & 7);
        w1bt[j * 128 + slot * 8 + (d & 7)] = f2bf(w1[d * EDIM + j]);
    }
    if (gid < EDIM * CDIM) {               // w2bt[k][j], linear
        int k = gid >> 7, jj = gid & 127;
        w2bt[k * 128 + jj] = f2bf(w2[jj * CDIM + k]);
    }
    if (gid < CDIM) {
        float a2 = 0.f;
        for (int dd = 0; dd < EDIM; ++dd)
            a2 += gelu_f(b1[dd]) * w2[dd * CDIM + gid];
        czero[gid] = a2;
    }
#pragma unroll
    for (int i = 0; i < 8; ++i)            // zero 32*64*64 partial sums
        csum_p[gid + i * 16384] = 0.f;
}

// ---------------- main: reg-LN -> MFMA MLP -> scatter-accumulate ------------
__global__ __launch_bounds__(256, 4)
void main_kernel(const float* __restrict__ x,
                 const float* __restrict__ ln1w, const float* __restrict__ ln1b,
                 const float* __restrict__ b1g,
                 const ushort* __restrict__ w1bt, const ushort* __restrict__ w2bt,
                 const float* __restrict__ czero,
                 const int* __restrict__ node_idx,
                 float* __restrict__ csum_p) {
    __shared__ ushort s_xn[TOKB * DD];     // 16KB bf16, swizzled
    __shared__ ushort s_h[TOKB * DD];      // 16KB bf16, swizzled
    __shared__ float  s_acc[LCOMP * CDIM]; // 2KB

    const int tid = threadIdx.x;
    const int w   = tid >> 6;
    const int ln  = tid & 63;
    const int cs  = ln >> 4;           // 4 lanes per token row
    const int row = w * 16 + (ln & 15);
    const int bid = blockIdx.x;
    const size_t base0 = (size_t)bid * (TOKB * TILES);

    s_acc[tid] = 0.f; s_acc[tid + 256] = 0.f;

    const float b1v0 = b1g[w * 32 + (ln & 15)];
    const float b1v1 = b1g[w * 32 + 16 + (ln & 15)];
    float czv[4];
#pragma unroll
    for (int kt = 0; kt < 4; ++kt) czv[kt] = czero[kt * 16 + (ln & 15)];

    // preload x for tile 0 (4 lanes/row, 32 contiguous floats each)
    float v[32];
    {
        const float* xp = x + (base0 + row) * DD + cs * 32;
#pragma unroll
        for (int sx = 0; sx < 8; ++sx) {
            float4 f = *(const float4*)(xp + sx * 4);
            v[sx*4+0]=f.x; v[sx*4+1]=f.y; v[sx*4+2]=f.z; v[sx*4+3]=f.w;
        }
    }

    for (int tile = 0; tile < TILES; ++tile) {
        // ---- LayerNorm in registers ----
        {
            float s = 0.f, q = 0.f;
#pragma unroll
            for (int i2 = 0; i2 < 32; ++i2) { s += v[i2]; q += v[i2]*v[i2]; }
            s += __shfl_xor(s, 16, 64); q += __shfl_xor(q, 16, 64);
            s += __shfl_xor(s, 32, 64); q += __shfl_xor(q, 32, 64);
            float m   = s * (1.f/128.f);
            float var = q * (1.f/128.f) - m*m;
            float rs  = rsqrtf(var + 1e-5f);
#pragma unroll
            for (int sx = 0; sx < 8; ++sx) {
                float4 w4 = *(const float4*)(ln1w + cs*32 + sx*4);
                float4 b4 = *(const float4*)(ln1b + cs*32 + sx*4);
                v[sx*4+0] = (v[sx*4+0]-m)*rs*w4.x + b4.x;
                v[sx*4+1] = (v[sx*4+1]-m)*rs*w4.y + b4.y;
                v[sx*4+2] = (v[sx*4+2]-m)*rs*w4.z + b4.z;
                v[sx*4+3] = (v[sx*4+3]-m)*rs*w4.w + b4.w;
            }
        }
        // write xn bf16 to LDS, swizzled
#pragma unroll
        for (int u = 0; u < 4; ++u) {
            uint4 pk;
            pk.x = f2bf(v[u*8+0]) | ((uint)f2bf(v[u*8+1]) << 16);
            pk.y = f2bf(v[u*8+2]) | ((uint)f2bf(v[u*8+3]) << 16);
            pk.z = f2bf(v[u*8+4]) | ((uint)f2bf(v[u*8+5]) << 16);
            pk.w = f2bf(v[u*8+6]) | ((uint)f2bf(v[u*8+7]) << 16);
            int slot = (cs * 4 + u) ^ (row & 7);
            *(uint4*)((char*)s_xn + row * 256 + slot * 16) = pk;
        }
        __syncthreads();   // sync1: xn visible (also covers s_acc init on tile 0)

        // prefetch next tile's x into v (overlaps GEMM1+GEMM2)
        if (tile + 1 < TILES) {
            const float* xp = x + (base0 + (tile + 1) * TOKB + row) * DD + cs * 32;
#pragma unroll
            for (int sx = 0; sx < 8; ++sx) {
                float4 f = *(const float4*)(xp + sx * 4);
                v[sx*4+0]=f.x; v[sx*4+1]=f.y; v[sx*4+2]=f.z; v[sx*4+3]=f.w;
            }
        }

        // ---- GEMM1: A = xn[64x128], B = w1[128x128]; wave owns 32 j ----
        bf16x8 b1f[2][4];
#pragma unroll
        for (int jt = 0; jt < 2; ++jt)
#pragma unroll
            for (int ks = 0; ks < 4; ++ks) {
                int jrow = w * 32 + jt * 16 + (ln & 15);
                int slot = (ks * 4 + cs) ^ (jrow & 7);
                b1f[jt][ks] = *(const bf16x8*)((const char*)w1bt + jrow * 256 + slot * 16);
            }
#pragma unroll
        for (int tt = 0; tt < 4; ++tt) {
            bf16x8 a4[4];
            int ar = tt * 16 + (ln & 15);
#pragma unroll
            for (int ks = 0; ks < 4; ++ks) {
                int slot = (ks * 4 + cs) ^ (ar & 7);
                a4[ks] = *(const bf16x8*)((const char*)s_xn + ar * 256 + slot * 16);
            }
            f32x4 ac0 = {0.f,0.f,0.f,0.f}, ac1 = {0.f,0.f,0.f,0.f};
#pragma unroll
            for (int ks = 0; ks < 4; ++ks) {
                ac0 = __builtin_amdgcn_mfma_f32_16x16x32_bf16(a4[ks], b1f[0][ks], ac0, 0, 0, 0);
                ac1 = __builtin_amdgcn_mfma_f32_16x16x32_bf16(a4[ks], b1f[1][ks], ac1, 0, 0, 0);
            }
            int hrb = tt * 16 + cs * 4;
            int j0  = w * 32 + (ln & 15);
            int j1  = j0 + 16;
#pragma unroll
            for (int r = 0; r < 4; ++r) {
                float h0 = gelu_f(ac0[r] + b1v0);
                float h1 = gelu_f(ac1[r] + b1v1);
                int hrow = hrb + r;
                int sl0 = (j0 >> 3) ^ (hrow & 7);
                int sl1 = (j1 >> 3) ^ (hrow & 7);
                *(ushort*)((char*)s_h + hrow*256 + sl0*16 + (j0 & 7)*2) = f2bf(h0);
                *(ushort*)((char*)s_h + hrow*256 + sl1*16 + (j1 & 7)*2) = f2bf(h1);
            }
        }
        __syncthreads();   // sync2: h complete

        // ---- GEMM2: A = h[16x128] (tile = wave), B = w2[128x64]; scatter ----
        {
            bf16x8 a4[4];
            int ar = w * 16 + (ln & 15);
#pragma unroll
            for (int ks = 0; ks < 4; ++ks) {
                int slot = (ks * 4 + cs) ^ (ar & 7);
                a4[ks] = *(const bf16x8*)((const char*)s_h + ar * 256 + slot * 16);
            }
            int tok0 = w * 16 + cs * 4;
            int4 li = *(const int4*)(node_idx + base0 + (size_t)tile * TOKB + tok0);
            int l0 = li.x >> 13, l1 = li.y >> 13, l2 = li.z >> 13, l3 = li.w >> 13;
#pragma unroll
            for (int kt = 0; kt < 4; ++kt) {
                bf16x8 bfr[4];
                int krow = kt * 16 + (ln & 15);
#pragma unroll
                for (int ks = 0; ks < 4; ++ks)
                    bfr[ks] = *(const bf16x8*)(w2bt + krow * EDIM + ks * 32 + cs * 8);
                f32x4 acc = {0.f,0.f,0.f,0.f};
#pragma unroll
                for (int ks = 0; ks < 4; ++ks)
                    acc = __builtin_amdgcn_mfma_f32_16x16x32_bf16(a4[ks], bfr[ks], acc, 0, 0, 0);
                int k = kt * 16 + (ln & 15);
                float czk = czv[kt];
                atomicAdd(&s_acc[l0 * CDIM + k], acc[0] - czk);
                atomicAdd(&s_acc[l1 * CDIM + k], acc[1] - czk);
                atomicAdd(&s_acc[l2 * CDIM + k], acc[2] - czk);
                atomicAdd(&s_acc[l3 * CDIM + k], acc[3] - czk);
            }
        }
        __syncthreads();   // scatter done before next tile overwrites xn/h
    }

    {   // flush block accumulator -> partial buffers
        int t8 = (bid >> 7) * LCOMP;    // 128 blocks per t
        int p  = bid & (NPART - 1);
#pragma unroll
        for (int i2 = 0; i2 < 2; ++i2) {
            int idx = tid + i2 * 256;
            int l = idx >> 6, k = idx & 63;
            atomicAdd(&csum_p[(p * 64 + t8 + l) * 64 + k], s_acc[idx]);
        }
    }
}

// ---------------- finalize: reduce partials, comp, LN(512), ortho loss ------
__global__ void fin_kernel(const float* __restrict__ csum_p, const float* __restrict__ czero,
                           const float* __restrict__ b2,
                           const float* __restrict__ lnfw, const float* __restrict__ lnfb,
                           float* __restrict__ out) {
    __shared__ float comp[TT * LCOMP * CDIM];
    __shared__ float norm_s[LCOMP], sum_s[LCOMP], red[8];
    int tid = threadIdx.x;

    for (int idx = tid; idx < TT * LCOMP * CDIM; idx += 512) {
        int bin = idx >> 6, k = idx & 63;
        float s = 0.f;
        for (int p = 0; p < NPART; ++p) s += csum_p[(p * 64 + bin) * 64 + k];
        comp[idx] = s * (1.f / GSZ) + czero[k] + b2[k];
    }
    __syncthreads();

    int wave = tid >> 6, lane = tid & 63;

    {   // per-t LayerNorm over 512
        int t = wave;
        float s = 0.f, q = 0.f;
        for (int e = lane; e < 512; e += 64) {
            float v = comp[t * 512 + e];
            s += v; q += v * v;
        }
#pragma unroll
        for (int off = 32; off > 0; off >>= 1) {
            s += __shfl_xor(s, off, 64);
            q += __shfl_xor(q, off, 64);
        }
        float m = s * (1.f / 512.f);
        float var = q * (1.f / 512.f) - m * m;
        float rs = rsqrtf(var + 1e-5f);
        for (int e = lane; e < 512; e += 64) {
            float v = comp[t * 512 + e];
            out[t * 512 + e] = (v - m) * rs * lnfw[e] + lnfb[e];
        }
    }

    {   // per-l norm and sum of f[l]
        int l = wave;
        float s2 = 0.f, s1 = 0.f;
        for (int qd = lane; qd < 512; qd += 64) {
            int t = qd >> 6, k = qd & 63;
            float v = comp[t * 512 + l * 64 + k];
            s2 += v * v; s1 += v;
        }
#pragma unroll
        for (int off = 32; off > 0; off >>= 1) {
            s2 += __shfl_xor(s2, off, 64);
            s1 += __shfl_xor(s1, off, 64);
        }
        if (lane == 0) { norm_s[l] = sqrtf(s2); sum_s[l] = s1; }
    }
    __syncthreads();

    float loss_part = 0.f;
    for (int p = wave; p < 49; p += 8) {
        int i = p / 7, j = 1 + p % 7;
        float d = 0.f;
        for (int qd = lane; qd < 512; qd += 64) {
            int t = qd >> 6, k = qd & 63;
            d += comp[t * 512 + i * 64 + k] * comp[t * 512 + j * 64 + k];
        }
#pragma unroll
        for (int off = 32; off > 0; off >>= 1) d += __shfl_xor(d, off, 64);
        float ni = norm_s[i], nj = norm_s[j];
        float dot = (d / (ni * nj)) / (sum_s[i] / ni + sum_s[j] / nj);
        loss_part += dot * dot;
    }
    if (lane == 0) red[wave] = loss_part;
    __syncthreads();
    if (tid == 0) {
        float tot = 0.f;
        for (int w2_ = 0; w2_ < 8; ++w2_) tot += red[w2_];
        out[4096] = tot * (1.f / 49.f);
    }
}

extern "C" void kernel_launch(void* const* d_in, const int* in_sizes, int n_in,
                              void* d_out, int out_size, void* d_ws, size_t ws_size,
                              hipStream_t stream) {
    const float* x    = (const float*)d_in[0];
    const float* ln1w = (const float*)d_in[1];
    const float* ln1b = (const float*)d_in[2];
    const float* w1   = (const float*)d_in[3];
    const float* b1   = (const float*)d_in[4];
    const float* w2   = (const float*)d_in[5];
    const float* b2   = (const float*)d_in[6];
    const float* lnfw = (const float*)d_in[7];
    const float* lnfb = (const float*)d_in[8];
    const int* node_idx = (const int*)d_in[10];
    float* out = (float*)d_out;

    char* wsb = (char*)d_ws;
    float*  czero  = (float*)(wsb + O_CZERO);
    ushort* w2bt   = (ushort*)(wsb + O_W2BT);
    ushort* w1bt   = (ushort*)(wsb + O_W1BT);
    float*  csum_p = (float*)(wsb + O_CSUMP);

    prep_kernel<<<64, 256, 0, stream>>>(w1, b1, w2, w1bt, w2bt, czero, csum_p);
    main_kernel<<<NBLK, 256, 0, stream>>>(x, ln1w, ln1b, b1, w1bt, w2bt, czero,
                                          node_idx, csum_p);
    fin_kernel<<<1, 512, 0, stream>>>(csum_p, czero, b2, lnfw, lnfb, out);
}

// Round 10
// 364.978 us; speedup vs baseline: 1.1574x; 1.1574x over previous
//
#include <hip/hip_runtime.h>
#include <math.h>

// Problem constants
#define TT 8
#define NTOK 32768
#define DD 128
#define LCOMP 8
#define GSZ 8192
#define CDIM 64
#define EDIM 128
#define NPART 32

#define TOKB 64                       // tokens per tile
#define TILES 4                       // tiles per block
#define NBLK (TT*NTOK/(TOKB*TILES))   // 1024

// workspace byte offsets
#define O_CZERO 0                            // 64 f32
#define O_W2BT  256                          // 64*128 bf16 = 16KB  [k][j]
#define O_W1BT  (256 + EDIM*CDIM*2)          // 128*128 bf16 = 32KB [j][d] swizzled
#define O_CSUMP (O_W1BT + DD*EDIM*2)         // 32*64*64 f32 = 512KB

typedef __attribute__((ext_vector_type(8))) short bf16x8;
typedef __attribute__((ext_vector_type(4))) float f32x4;

__device__ __forceinline__ ushort f2bf(float f) {
    union { float f; uint u; } c; c.f = f;
    uint u = c.u;
    return (ushort)((u + 0x7FFFu + ((u >> 16) & 1u)) >> 16);
}

// gelu via Abramowitz-Stegun 7.1.26 erf (|eps| <= 1.5e-7)
__device__ __forceinline__ float gelu_f(float a) {
    float x = a * 0.70710678118654752f;
    float ax = fabsf(x);
    float t = 1.0f / (1.0f + 0.3275911f * ax);
    float p = t * (0.254829592f + t * (-0.284496736f + t * (1.421413741f +
              t * (-1.453152027f + t * 1.061405429f))));
    float e = __expf(-x * x);
    float er = copysignf(1.0f - p * e, x);
    return 0.5f * a * (1.0f + er);
}

// ---------------- prep: bf16 transposed weights, czero, zero csum_p ---------
__global__ void prep_kernel(const float* __restrict__ w1, const float* __restrict__ b1,
                            const float* __restrict__ w2,
                            ushort* __restrict__ w1bt, ushort* __restrict__ w2bt,
                            float* __restrict__ czero, float* __restrict__ csum_p) {
    int gid = blockIdx.x * 256 + threadIdx.x;
    if (gid < DD * EDIM) {                 // w1bt[j][d], 16B-chunk XOR swizzled by (j&7)
        int j = gid >> 7, d = gid & 127;
        int slot = (d >> 3) ^ (j & 7);
        w1bt[j * 128 + slot * 8 + (d & 7)] = f2bf(w1[d * EDIM + j]);
    }
    if (gid < EDIM * CDIM) {               // w2bt[k][j], linear
        int k = gid >> 7, jj = gid & 127;
        w2bt[k * 128 + jj] = f2bf(w2[jj * CDIM + k]);
    }
    if (gid < CDIM) {
        float a2 = 0.f;
        for (int dd = 0; dd < EDIM; ++dd)
            a2 += gelu_f(b1[dd]) * w2[dd * CDIM + gid];
        czero[gid] = a2;
    }
#pragma unroll
    for (int i = 0; i < 8; ++i)            // zero 32*64*64 partial sums
        csum_p[gid + i * 16384] = 0.f;
}

// ---------------- main: reg-LN -> MFMA MLP -> scatter-accumulate ------------
// launch_bounds (256,2): round-9 A/B showed (256,4) forces VGPR=64 and spills
// v[32]+frags to scratch (WRITE_SIZE 8->182MB, FETCH 66->424MB, 252us).
// (256,2) measured 124 VGPR / no spills in the round-2 variant of this code.
__global__ __launch_bounds__(256, 2)
void main_kernel(const float* __restrict__ x,
                 const float* __restrict__ ln1w, const float* __restrict__ ln1b,
                 const float* __restrict__ b1g,
                 const ushort* __restrict__ w1bt, const ushort* __restrict__ w2bt,
                 const float* __restrict__ czero,
                 const int* __restrict__ node_idx,
                 float* __restrict__ csum_p) {
    __shared__ ushort s_xn[TOKB * DD];     // 16KB bf16, swizzled
    __shared__ ushort s_h[TOKB * DD];      // 16KB bf16, swizzled
    __shared__ float  s_acc[LCOMP * CDIM]; // 2KB

    const int tid = threadIdx.x;
    const int w   = tid >> 6;
    const int ln  = tid & 63;
    const int cs  = ln >> 4;           // 4 lanes per token row
    const int row = w * 16 + (ln & 15);
    const int bid = blockIdx.x;
    const size_t base0 = (size_t)bid * (TOKB * TILES);

    s_acc[tid] = 0.f; s_acc[tid + 256] = 0.f;

    const float b1v0 = b1g[w * 32 + (ln & 15)];
    const float b1v1 = b1g[w * 32 + 16 + (ln & 15)];
    float czv[4];
#pragma unroll
    for (int kt = 0; kt < 4; ++kt) czv[kt] = czero[kt * 16 + (ln & 15)];

    // preload x for tile 0 (4 lanes/row, 32 contiguous floats each)
    float v[32];
    {
        const float* xp = x + (base0 + row) * DD + cs * 32;
#pragma unroll
        for (int sx = 0; sx < 8; ++sx) {
            float4 f = *(const float4*)(xp + sx * 4);
            v[sx*4+0]=f.x; v[sx*4+1]=f.y; v[sx*4+2]=f.z; v[sx*4+3]=f.w;
        }
    }

    for (int tile = 0; tile < TILES; ++tile) {
        // ---- LayerNorm in registers ----
        {
            float s = 0.f, q = 0.f;
#pragma unroll
            for (int i2 = 0; i2 < 32; ++i2) { s += v[i2]; q += v[i2]*v[i2]; }
            s += __shfl_xor(s, 16, 64); q += __shfl_xor(q, 16, 64);
            s += __shfl_xor(s, 32, 64); q += __shfl_xor(q, 32, 64);
            float m   = s * (1.f/128.f);
            float var = q * (1.f/128.f) - m*m;
            float rs  = rsqrtf(var + 1e-5f);
#pragma unroll
            for (int sx = 0; sx < 8; ++sx) {
                float4 w4 = *(const float4*)(ln1w + cs*32 + sx*4);
                float4 b4 = *(const float4*)(ln1b + cs*32 + sx*4);
                v[sx*4+0] = (v[sx*4+0]-m)*rs*w4.x + b4.x;
                v[sx*4+1] = (v[sx*4+1]-m)*rs*w4.y + b4.y;
                v[sx*4+2] = (v[sx*4+2]-m)*rs*w4.z + b4.z;
                v[sx*4+3] = (v[sx*4+3]-m)*rs*w4.w + b4.w;
            }
        }
        // write xn bf16 to LDS, swizzled
#pragma unroll
        for (int u = 0; u < 4; ++u) {
            uint4 pk;
            pk.x = f2bf(v[u*8+0]) | ((uint)f2bf(v[u*8+1]) << 16);
            pk.y = f2bf(v[u*8+2]) | ((uint)f2bf(v[u*8+3]) << 16);
            pk.z = f2bf(v[u*8+4]) | ((uint)f2bf(v[u*8+5]) << 16);
            pk.w = f2bf(v[u*8+6]) | ((uint)f2bf(v[u*8+7]) << 16);
            int slot = (cs * 4 + u) ^ (row & 7);
            *(uint4*)((char*)s_xn + row * 256 + slot * 16) = pk;
        }
        __syncthreads();   // sync1: xn visible (also covers s_acc init on tile 0)

        // prefetch next tile's x into v (overlaps GEMM1+GEMM2)
        if (tile + 1 < TILES) {
            const float* xp = x + (base0 + (tile + 1) * TOKB + row) * DD + cs * 32;
#pragma unroll
            for (int sx = 0; sx < 8; ++sx) {
                float4 f = *(const float4*)(xp + sx * 4);
                v[sx*4+0]=f.x; v[sx*4+1]=f.y; v[sx*4+2]=f.z; v[sx*4+3]=f.w;
            }
        }

        // ---- GEMM1: A = xn[64x128], B = w1[128x128]; wave owns 32 j ----
        bf16x8 b1f[2][4];
#pragma unroll
        for (int jt = 0; jt < 2; ++jt)
#pragma unroll
            for (int ks = 0; ks < 4; ++ks) {
                int jrow = w * 32 + jt * 16 + (ln & 15);
                int slot = (ks * 4 + cs) ^ (jrow & 7);
                b1f[jt][ks] = *(const bf16x8*)((const char*)w1bt + jrow * 256 + slot * 16);
            }
#pragma unroll
        for (int tt = 0; tt < 4; ++tt) {
            bf16x8 a4[4];
            int ar = tt * 16 + (ln & 15);
#pragma unroll
            for (int ks = 0; ks < 4; ++ks) {
                int slot = (ks * 4 + cs) ^ (ar & 7);
                a4[ks] = *(const bf16x8*)((const char*)s_xn + ar * 256 + slot * 16);
            }
            f32x4 ac0 = {0.f,0.f,0.f,0.f}, ac1 = {0.f,0.f,0.f,0.f};
#pragma unroll
            for (int ks = 0; ks < 4; ++ks) {
                ac0 = __builtin_amdgcn_mfma_f32_16x16x32_bf16(a4[ks], b1f[0][ks], ac0, 0, 0, 0);
                ac1 = __builtin_amdgcn_mfma_f32_16x16x32_bf16(a4[ks], b1f[1][ks], ac1, 0, 0, 0);
            }
            int hrb = tt * 16 + cs * 4;
            int j0  = w * 32 + (ln & 15);
            int j1  = j0 + 16;
#pragma unroll
            for (int r = 0; r < 4; ++r) {
                float h0 = gelu_f(ac0[r] + b1v0);
                float h1 = gelu_f(ac1[r] + b1v1);
                int hrow = hrb + r;
                int sl0 = (j0 >> 3) ^ (hrow & 7);
                int sl1 = (j1 >> 3) ^ (hrow & 7);
                *(ushort*)((char*)s_h + hrow*256 + sl0*16 + (j0 & 7)*2) = f2bf(h0);
                *(ushort*)((char*)s_h + hrow*256 + sl1*16 + (j1 & 7)*2) = f2bf(h1);
            }
        }
        __syncthreads();   // sync2: h complete

        // ---- GEMM2: A = h[16x128] (tile = wave), B = w2[128x64]; scatter ----
        {
            bf16x8 a4[4];
            int ar = w * 16 + (ln & 15);
#pragma unroll
            for (int ks = 0; ks < 4; ++ks) {
                int slot = (ks * 4 + cs) ^ (ar & 7);
                a4[ks] = *(const bf16x8*)((const char*)s_h + ar * 256 + slot * 16);
            }
            int tok0 = w * 16 + cs * 4;
            int4 li = *(const int4*)(node_idx + base0 + (size_t)tile * TOKB + tok0);
            int l0 = li.x >> 13, l1 = li.y >> 13, l2 = li.z >> 13, l3 = li.w >> 13;
#pragma unroll
            for (int kt = 0; kt < 4; ++kt) {
                bf16x8 bfr[4];
                int krow = kt * 16 + (ln & 15);
#pragma unroll
                for (int ks = 0; ks < 4; ++ks)
                    bfr[ks] = *(const bf16x8*)(w2bt + krow * EDIM + ks * 32 + cs * 8);
                f32x4 acc = {0.f,0.f,0.f,0.f};
#pragma unroll
                for (int ks = 0; ks < 4; ++ks)
                    acc = __builtin_amdgcn_mfma_f32_16x16x32_bf16(a4[ks], bfr[ks], acc, 0, 0, 0);
                int k = kt * 16 + (ln & 15);
                float czk = czv[kt];
                atomicAdd(&s_acc[l0 * CDIM + k], acc[0] - czk);
                atomicAdd(&s_acc[l1 * CDIM + k], acc[1] - czk);
                atomicAdd(&s_acc[l2 * CDIM + k], acc[2] - czk);
                atomicAdd(&s_acc[l3 * CDIM + k], acc[3] - czk);
            }
        }
        __syncthreads();   // scatter done before next tile overwrites xn/h
    }

    {   // flush block accumulator -> partial buffers
        int t8 = (bid >> 7) * LCOMP;    // 128 blocks per t
        int p  = bid & (NPART - 1);
#pragma unroll
        for (int i2 = 0; i2 < 2; ++i2) {
            int idx = tid + i2 * 256;
            int l = idx >> 6, k = idx & 63;
            atomicAdd(&csum_p[(p * 64 + t8 + l) * 64 + k], s_acc[idx]);
        }
    }
}

// ---------------- finalize: reduce partials, comp, LN(512), ortho loss ------
__global__ void fin_kernel(const float* __restrict__ csum_p, const float* __restrict__ czero,
                           const float* __restrict__ b2,
                           const float* __restrict__ lnfw, const float* __restrict__ lnfb,
                           float* __restrict__ out) {
    __shared__ float comp[TT * LCOMP * CDIM];
    __shared__ float norm_s[LCOMP], sum_s[LCOMP], red[8];
    int tid = threadIdx.x;

    for (int idx = tid; idx < TT * LCOMP * CDIM; idx += 512) {
        int bin = idx >> 6, k = idx & 63;
        float s = 0.f;
        for (int p = 0; p < NPART; ++p) s += csum_p[(p * 64 + bin) * 64 + k];
        comp[idx] = s * (1.f / GSZ) + czero[k] + b2[k];
    }
    __syncthreads();

    int wave = tid >> 6, lane = tid & 63;

    {   // per-t LayerNorm over 512
        int t = wave;
        float s = 0.f, q = 0.f;
        for (int e = lane; e < 512; e += 64) {
            float v = comp[t * 512 + e];
            s += v; q += v * v;
        }
#pragma unroll
        for (int off = 32; off > 0; off >>= 1) {
            s += __shfl_xor(s, off, 64);
            q += __shfl_xor(q, off, 64);
        }
        float m = s * (1.f / 512.f);
        float var = q * (1.f / 512.f) - m * m;
        float rs = rsqrtf(var + 1e-5f);
        for (int e = lane; e < 512; e += 64) {
            float v = comp[t * 512 + e];
            out[t * 512 + e] = (v - m) * rs * lnfw[e] + lnfb[e];
        }
    }

    {   // per-l norm and sum of f[l]
        int l = wave;
        float s2 = 0.f, s1 = 0.f;
        for (int qd = lane; qd < 512; qd += 64) {
            int t = qd >> 6, k = qd & 63;
            float v = comp[t * 512 + l * 64 + k];
            s2 += v * v; s1 += v;
        }
#pragma unroll
        for (int off = 32; off > 0; off >>= 1) {
            s2 += __shfl_xor(s2, off, 64);
            s1 += __shfl_xor(s1, off, 64);
        }
        if (lane == 0) { norm_s[l] = sqrtf(s2); sum_s[l] = s1; }
    }
    __syncthreads();

    float loss_part = 0.f;
    for (int p = wave; p < 49; p += 8) {
        int i = p / 7, j = 1 + p % 7;
        float d = 0.f;
        for (int qd = lane; qd < 512; qd += 64) {
            int t = qd >> 6, k = qd & 63;
            d += comp[t * 512 + i * 64 + k] * comp[t * 512 + j * 64 + k];
        }
#pragma unroll
        for (int off = 32; off > 0; off >>= 1) d += __shfl_xor(d, off, 64);
        float ni = norm_s[i], nj = norm_s[j];
        float dot = (d / (ni * nj)) / (sum_s[i] / ni + sum_s[j] / nj);
        loss_part += dot * dot;
    }
    if (lane == 0) red[wave] = loss_part;
    __syncthreads();
    if (tid == 0) {
        float tot = 0.f;
        for (int w2_ = 0; w2_ < 8; ++w2_) tot += red[w2_];
        out[4096] = tot * (1.f / 49.f);
    }
}

extern "C" void kernel_launch(void* const* d_in, const int* in_sizes, int n_in,
                              void* d_out, int out_size, void* d_ws, size_t ws_size,
                              hipStream_t stream) {
    const float* x    = (const float*)d_in[0];
    const float* ln1w = (const float*)d_in[1];
    const float* ln1b = (const float*)d_in[2];
    const float* w1   = (const float*)d_in[3];
    const float* b1   = (const float*)d_in[4];
    const float* w2   = (const float*)d_in[5];
    const float* b2   = (const float*)d_in[6];
    const float* lnfw = (const float*)d_in[7];
    const float* lnfb = (const float*)d_in[8];
    const int* node_idx = (const int*)d_in[10];
    float* out = (float*)d_out;

    char* wsb = (char*)d_ws;
    float*  czero  = (float*)(wsb + O_CZERO);
    ushort* w2bt   = (ushort*)(wsb + O_W2BT);
    ushort* w1bt   = (ushort*)(wsb + O_W1BT);
    float*  csum_p = (float*)(wsb + O_CSUMP);

    prep_kernel<<<64, 256, 0, stream>>>(w1, b1, w2, w1bt, w2bt, czero, csum_p);
    main_kernel<<<NBLK, 256, 0, stream>>>(x, ln1w, ln1b, b1, w1bt, w2bt, czero,
                                          node_idx, csum_p);
    fin_kernel<<<1, 512, 0, stream>>>(csum_p, czero, b2, lnfw, lnfb, out);
}